// Round 1
// baseline (1661.826 us; speedup 1.0000x reference)
//
#include <hip/hip_runtime.h>

// Performer (FAVOR+) attention, fp32 baseline, fused two-pass.
// b=4 h=8 L=8192 d=64 m=256. No q'/k' materialization in HBM.

#define BH 32
#define LL 8192
#define DD 64
#define MM 256
#define NRM 0.35355339059327373f   // 64^-0.25
#define EPSK 1e-6f
#define EPSZ 1e-6f

#define CHUNKA 16
#define LCA (LL / CHUNKA)          // 512 rows per block
#define TILE 16
#define KSTRIDE 68                 // pad 64->68: keeps 16B align, breaks bank stride

#define CHUNKB 8
#define LCB (LL / CHUNKB)          // 1024 rows per block
#define RG 64                      // rows per group in kernel B
#define QSTRIDE 68
#define QPSTRIDE 257               // conflict-free for 16 distinct rows/wave

// ---------------- Kernel A: kv[bh,m,d] += k'^T v ; ksum[bh,m] += sum k' ----
__global__ __launch_bounds__(256) void kv_ksum_kernel(
    const float* __restrict__ kin, const float* __restrict__ vin,
    const float* __restrict__ Pm, float* __restrict__ kv, float* __restrict__ ksum)
{
    __shared__ __align__(16) float k_lds[TILE * KSTRIDE];
    __shared__ __align__(16) float v_lds[TILE * KSTRIDE];
    __shared__ float sq_lds[TILE];
    const int t = threadIdx.x;
    const int bh = blockIdx.x / CHUNKA;
    const int chunk = blockIdx.x % CHUNKA;

    // thread t owns projection row m=t, NRM folded in
    float preg[DD];
#pragma unroll
    for (int d = 0; d < DD; d += 4) {
        float4 p4 = *(const float4*)(Pm + t * DD + d);
        preg[d+0] = p4.x * NRM; preg[d+1] = p4.y * NRM;
        preg[d+2] = p4.z * NRM; preg[d+3] = p4.w * NRM;
    }
    float acc[DD];
#pragma unroll
    for (int d = 0; d < DD; ++d) acc[d] = 0.f;
    float ksacc = 0.f;

    const float* kb = kin + ((size_t)bh * LL + (size_t)chunk * LCA) * DD;
    const float* vb = vin + ((size_t)bh * LL + (size_t)chunk * LCA) * DD;

    const int sr = t >> 4;          // staging: thread t covers floats [4t,4t+4)
    const int sd = (t & 15) * 4;    // of the 16x64 tile

    for (int l0 = 0; l0 < LCA; l0 += TILE) {
        __syncthreads();            // protect prev-iter readers
        {
            const int gi = l0 * DD + t * 4;
            *(float4*)(k_lds + sr * KSTRIDE + sd) = *(const float4*)(kb + gi);
            *(float4*)(v_lds + sr * KSTRIDE + sd) = *(const float4*)(vb + gi);
        }
        __syncthreads();
        if (t < TILE) {
            float s = 0.f;
#pragma unroll
            for (int d = 0; d < DD; ++d) { float x = k_lds[t * KSTRIDE + d]; s += x * x; }
            sq_lds[t] = 0.5f * NRM * NRM * s;
        }
        __syncthreads();
#pragma unroll 2
        for (int r = 0; r < TILE; ++r) {
            float proj = 0.f;
#pragma unroll
            for (int d = 0; d < DD; ++d) proj += preg[d] * k_lds[r * KSTRIDE + d]; // broadcast reads
            float w = __expf(proj - sq_lds[r] + EPSK);
            ksacc += w;
#pragma unroll
            for (int d = 0; d < DD; ++d) acc[d] += w * v_lds[r * KSTRIDE + d];     // broadcast reads
        }
    }
    float* kvp = kv + (size_t)bh * MM * DD + t * DD;
#pragma unroll
    for (int d = 0; d < DD; ++d) atomicAdd(kvp + d, acc[d]);
    atomicAdd(ksum + bh * MM + t, ksacc);
}

// ---------------- Kernel B: out[l,d] = z_l * sum_m q'[l,m] kv[m,d] ---------
__global__ __launch_bounds__(256) void out_kernel(
    const float* __restrict__ qin, const float* __restrict__ Pm,
    const float* __restrict__ kv, const float* __restrict__ ksum,
    float* __restrict__ out)
{
    __shared__ __align__(16) float kv_lds[MM * DD];        // 64 KB
    __shared__ float ks_lds[MM];                            // 1 KB
    __shared__ __align__(16) float q_lds[RG * QSTRIDE];     // 17 KB
    __shared__ float qp_lds[RG * QPSTRIDE];                 // 64.25 KB
    __shared__ float sq_lds[RG];
    const int t = threadIdx.x;
    const int bh = blockIdx.x / CHUNKB;
    const int chunk = blockIdx.x % CHUNKB;

    float preg[DD];
#pragma unroll
    for (int d = 0; d < DD; d += 4) {
        float4 p4 = *(const float4*)(Pm + t * DD + d);
        preg[d+0] = p4.x * NRM; preg[d+1] = p4.y * NRM;
        preg[d+2] = p4.z * NRM; preg[d+3] = p4.w * NRM;
    }
    // stage kv + ksum for this bh (written by kernel A)
    const float* kvg = kv + (size_t)bh * MM * DD;
    for (int i = t * 4; i < MM * DD; i += 1024)
        *(float4*)(kv_lds + i) = *(const float4*)(kvg + i);
    ks_lds[t] = ksum[bh * MM + t];

    const float* qb = qin + ((size_t)bh * LL + (size_t)chunk * LCB) * DD;
    float* ob = out + ((size_t)bh * LL + (size_t)chunk * LCB) * DD;

    const int r = t >> 2;           // phase-2 row (0..63)
    const int dblk = t & 3;         // phase-2 16-wide d slice

    for (int g = 0; g < LCB / RG; ++g) {
        __syncthreads();            // also covers kv_lds staging on g==0
        for (int i4 = t; i4 < RG * DD / 4; i4 += 256) {
            const int i = i4 * 4;
            *(float4*)(q_lds + (i >> 6) * QSTRIDE + (i & 63)) =
                *(const float4*)(qb + (size_t)g * RG * DD + i);
        }
        __syncthreads();
        if (t < RG) {
            float s = 0.f;
#pragma unroll
            for (int d = 0; d < DD; ++d) { float x = q_lds[t * QSTRIDE + d]; s += x * x; }
            sq_lds[t] = 0.5f * NRM * NRM * s;
        }
        __syncthreads();
        // phase 1: thread t = m, compute q' for RG rows
#pragma unroll 2
        for (int rr = 0; rr < RG; ++rr) {
            float proj = 0.f;
#pragma unroll
            for (int d = 0; d < DD; ++d) proj += preg[d] * q_lds[rr * QSTRIDE + d];
            qp_lds[rr * QPSTRIDE + t] = __expf(proj - sq_lds[rr] + EPSK);
        }
        __syncthreads();
        // phase 2: thread (r, dblk) -> out[row, dblk*16 .. +15]
        float4 o0 = make_float4(0,0,0,0), o1 = o0, o2 = o0, o3 = o0;
        const float* qprow = qp_lds + r * QPSTRIDE;
        const float* kvcol = kv_lds + dblk * 16;
#pragma unroll 4
        for (int m = 0; m < MM; ++m) {
            const float w = qprow[m];                              // 16-lane broadcast
            const float4* kv4 = (const float4*)(kvcol + m * DD);   // 4-address broadcast
            float4 a = kv4[0], b2 = kv4[1], c = kv4[2], e = kv4[3];
            o0.x += w*a.x;  o0.y += w*a.y;  o0.z += w*a.z;  o0.w += w*a.w;
            o1.x += w*b2.x; o1.y += w*b2.y; o1.z += w*b2.z; o1.w += w*b2.w;
            o2.x += w*c.x;  o2.y += w*c.y;  o2.z += w*c.z;  o2.w += w*c.w;
            o3.x += w*e.x;  o3.y += w*e.y;  o3.z += w*e.z;  o3.w += w*e.w;
        }
        // z: each of the 4 lanes of a row sums a quarter of m, then 4-lane reduce
        float zacc = 0.f;
#pragma unroll 8
        for (int mm = 0; mm < 64; ++mm)
            zacc += qprow[dblk * 64 + mm] * ks_lds[dblk * 64 + mm];
        zacc += __shfl_xor(zacc, 1);
        zacc += __shfl_xor(zacc, 2);
        const float z = 1.f / (zacc + EPSZ);

        float* op = ob + ((size_t)g * RG + r) * DD + dblk * 16;
        float4 s0 = make_float4(o0.x*z, o0.y*z, o0.z*z, o0.w*z);
        float4 s1 = make_float4(o1.x*z, o1.y*z, o1.z*z, o1.w*z);
        float4 s2 = make_float4(o2.x*z, o2.y*z, o2.z*z, o2.w*z);
        float4 s3 = make_float4(o3.x*z, o3.y*z, o3.z*z, o3.w*z);
        ((float4*)op)[0] = s0; ((float4*)op)[1] = s1;
        ((float4*)op)[2] = s2; ((float4*)op)[3] = s3;
    }
}

extern "C" void kernel_launch(void* const* d_in, const int* in_sizes, int n_in,
                              void* d_out, int out_size, void* d_ws, size_t ws_size,
                              hipStream_t stream) {
    const float* q  = (const float*)d_in[0];
    const float* k  = (const float*)d_in[1];
    const float* v  = (const float*)d_in[2];
    const float* Pm = (const float*)d_in[3];
    float* out = (float*)d_out;

    float* kv   = (float*)d_ws;            // [BH, M, D]
    float* ksum = kv + (size_t)BH * MM * DD; // [BH, M]

    hipMemsetAsync(d_ws, 0, ((size_t)BH * MM * DD + (size_t)BH * MM) * sizeof(float), stream);
    hipLaunchKernelGGL(kv_ksum_kernel, dim3(BH * CHUNKA), dim3(256), 0, stream,
                       k, v, Pm, kv, ksum);
    hipLaunchKernelGGL(out_kernel, dim3(BH * CHUNKB), dim3(256), 0, stream,
                       q, Pm, kv, ksum, out);
}

// Round 2
// 323.942 us; speedup vs baseline: 5.1300x; 5.1300x over previous
//
#include <hip/hip_runtime.h>
#include <hip/hip_bf16.h>

// Performer (FAVOR+) attention, bf16-MFMA fused two-pass.
// b=4 h=8 L=8192 d=64 m=256.
// A: stream K,V -> kv[bh,256,64] (+ksum) via proj-MFMA -> exp -> K'^T V MFMA.
// B: stream Q -> proj-MFMA -> exp -> Q'kv MFMA, z from in-reg partials.

#define BH 32
#define LL 8192
#define DD 64
#define MM 256
#define NRM 0.35355339059327373f   // 64^-0.25
#define SQS 0.0625f                // 0.5*NRM^2
#define EPSK 1e-6f
#define EPSZ 1e-6f

typedef __attribute__((ext_vector_type(8))) short bf16x8;
typedef __attribute__((ext_vector_type(4))) float f32x4;
#define MFMA(a, b, c) __builtin_amdgcn_mfma_f32_16x16x32_bf16(a, b, c, 0, 0, 0)

static __device__ __forceinline__ short f2bf(float x) {
    union { float f; unsigned u; } c{x};
    unsigned r = c.u + 0x7fffu + ((c.u >> 16) & 1u);   // RNE
    return (short)(r >> 16);
}

// Load P as MFMA B-operand fragments (NRM folded): pb[ks][mt],
// element jj = P[64*wv + mt*16 + (lane&15)][ks*32 + quad*8 + jj] * NRM
static __device__ __forceinline__ void load_pfrags(
    const float* __restrict__ Pm, int wv, int quad, int l16, bf16x8 pb[2][4])
{
#pragma unroll
    for (int ks = 0; ks < 2; ++ks)
#pragma unroll
        for (int mt = 0; mt < 4; ++mt) {
            const float* pr = Pm + (wv * 64 + mt * 16 + l16) * DD + ks * 32 + quad * 8;
            float4 p0 = *(const float4*)pr;
            float4 p1 = *(const float4*)(pr + 4);
            bf16x8 f;
            f[0] = f2bf(p0.x * NRM); f[1] = f2bf(p0.y * NRM);
            f[2] = f2bf(p0.z * NRM); f[3] = f2bf(p0.w * NRM);
            f[4] = f2bf(p1.x * NRM); f[5] = f2bf(p1.y * NRM);
            f[6] = f2bf(p1.z * NRM); f[7] = f2bf(p1.w * NRM);
            pb[ks][mt] = f;
        }
}

// ---------------- Kernel A: kv += K'^T V, ksum += colsum(K') ----------------
__global__ __launch_bounds__(256, 2) void kv_kernel(
    const float* __restrict__ kin, const float* __restrict__ vin,
    const float* __restrict__ Pm, float* __restrict__ kv, float* __restrict__ ksum)
{
    __shared__ short Kb[32 * 72];    // K tile bf16 [l][d], stride 72 (144B rows, 16B-aligned)
    __shared__ short Vt[64 * 40];    // V^T tile   [d][l], stride 40 (80B rows)
    __shared__ short Ktp[256 * 40];  // K'^T tile  [m][l], stride 40
    __shared__ float cl_lds[32];     // eps - 0.5*NRM^2*|k|^2 per row

    const int t = threadIdx.x;
    const int lane = t & 63, wv = t >> 6;
    const int quad = lane >> 4, l16 = lane & 15;
    const int bh = blockIdx.x >> 4, chunk = blockIdx.x & 15;

    bf16x8 pb[2][4];
    load_pfrags(Pm, wv, quad, l16, pb);

    f32x4 kvacc[4][4];
#pragma unroll
    for (int mt = 0; mt < 4; ++mt)
#pragma unroll
        for (int dt = 0; dt < 4; ++dt) kvacc[mt][dt] = (f32x4)0.f;
    float ksacc[4] = {0.f, 0.f, 0.f, 0.f};

    const size_t base = ((size_t)bh * LL + (size_t)chunk * 512) * DD;
    const float* kb = kin + base;
    const float* vb = vin + base;
    const int sl = t >> 4, sd4 = t & 15;

    for (int tile = 0; tile < 16; ++tile) {
        __syncthreads();
        // --- stage: K -> Kb (bf16), V -> Vt (transposed bf16), row norms ---
#pragma unroll
        for (int half = 0; half < 2; ++half) {
            const int l = sl + half * 16;
            const int gi = (tile * 32 + l) * DD + sd4 * 4;
            float4 kf = *(const float4*)(kb + gi);
            float sq = kf.x * kf.x + kf.y * kf.y + kf.z * kf.z + kf.w * kf.w;
            sq += __shfl_xor(sq, 1); sq += __shfl_xor(sq, 2);
            sq += __shfl_xor(sq, 4); sq += __shfl_xor(sq, 8);
            if (sd4 == 0) cl_lds[l] = EPSK - SQS * sq;
            union { short s[4]; unsigned long long u; } uk;
            uk.s[0] = f2bf(kf.x); uk.s[1] = f2bf(kf.y);
            uk.s[2] = f2bf(kf.z); uk.s[3] = f2bf(kf.w);
            *(unsigned long long*)&Kb[l * 72 + sd4 * 4] = uk.u;
            float4 vf = *(const float4*)(vb + gi);
            Vt[(sd4 * 4 + 0) * 40 + l] = f2bf(vf.x);
            Vt[(sd4 * 4 + 1) * 40 + l] = f2bf(vf.y);
            Vt[(sd4 * 4 + 2) * 40 + l] = f2bf(vf.z);
            Vt[(sd4 * 4 + 3) * 40 + l] = f2bf(vf.w);
        }
        __syncthreads();
        // --- proj MFMA: pt[lt][mt] = (K*NRM) P^T, wave owns m-chunk 64*wv ---
        f32x4 pt[2][4];
#pragma unroll
        for (int lt = 0; lt < 2; ++lt)
#pragma unroll
            for (int mt = 0; mt < 4; ++mt) pt[lt][mt] = (f32x4)0.f;
#pragma unroll
        for (int ks = 0; ks < 2; ++ks)
#pragma unroll
            for (int lt = 0; lt < 2; ++lt) {
                bf16x8 af = *(bf16x8*)&Kb[(lt * 16 + l16) * 72 + ks * 32 + quad * 8];
#pragma unroll
                for (int mt = 0; mt < 4; ++mt)
                    pt[lt][mt] = MFMA(af, pb[ks][mt], pt[lt][mt]);
            }
        // --- exp -> K', accumulate ksum, write K'^T[m][l] (b64, l-contig) ---
        float cl[2][4];
#pragma unroll
        for (int lt = 0; lt < 2; ++lt)
#pragma unroll
            for (int r = 0; r < 4; ++r) cl[lt][r] = cl_lds[lt * 16 + quad * 4 + r];
#pragma unroll
        for (int lt = 0; lt < 2; ++lt)
#pragma unroll
            for (int mt = 0; mt < 4; ++mt) {
                union { short s[4]; unsigned long long u; } uo;
#pragma unroll
                for (int r = 0; r < 4; ++r) {
                    float w = __expf(pt[lt][mt][r] + cl[lt][r]);
                    ksacc[mt] += w;
                    uo.s[r] = f2bf(w);
                }
                *(unsigned long long*)&Ktp[(wv * 64 + mt * 16 + l16) * 40 + lt * 16 + quad * 4] = uo.u;
            }
        // --- kv MFMA: kv[m][d] += sum_l K'^T[m][l] V[l][d], K = 32 = one step ---
        bf16x8 aK[4], bV[4];
#pragma unroll
        for (int mt = 0; mt < 4; ++mt)
            aK[mt] = *(bf16x8*)&Ktp[(wv * 64 + mt * 16 + l16) * 40 + quad * 8];
#pragma unroll
        for (int dt = 0; dt < 4; ++dt)
            bV[dt] = *(bf16x8*)&Vt[(dt * 16 + l16) * 40 + quad * 8];
#pragma unroll
        for (int mt = 0; mt < 4; ++mt)
#pragma unroll
            for (int dt = 0; dt < 4; ++dt)
                kvacc[mt][dt] = MFMA(aK[mt], bV[dt], kvacc[mt][dt]);
    }
    // --- epilogue: atomics into workspace ---
    float* kvg = kv + (size_t)bh * MM * DD;
#pragma unroll
    for (int mt = 0; mt < 4; ++mt) {
        float r = ksacc[mt];
        r += __shfl_xor(r, 16); r += __shfl_xor(r, 32);
        if (quad == 0) atomicAdd(ksum + bh * MM + wv * 64 + mt * 16 + l16, r);
#pragma unroll
        for (int dt = 0; dt < 4; ++dt)
#pragma unroll
            for (int rg = 0; rg < 4; ++rg)
                atomicAdd(kvg + (wv * 64 + mt * 16 + quad * 4 + rg) * DD + dt * 16 + l16,
                          kvacc[mt][dt][rg]);
    }
}

// ---------------- Kernel B: out = (Q' kv) * z ------------------------------
__global__ __launch_bounds__(256, 2) void out_kernel(
    const float* __restrict__ qin, const float* __restrict__ Pm,
    const float* __restrict__ kv, const float* __restrict__ ksum,
    float* __restrict__ out)
{
    __shared__ short Qb[32 * 72];     // Q tile bf16 [l][d]
    __shared__ short Qp[32 * 264];    // Q' tile bf16 [l][m], stride 264 (528B rows)
    __shared__ short kvT[64 * 264];   // kv^T bf16 [d][m]
    __shared__ float ks_lds[MM];
    __shared__ float cl_lds[32];
    __shared__ float z_lds[32];

    const int t = threadIdx.x;
    const int lane = t & 63, wv = t >> 6;
    const int quad = lane >> 4, l16 = lane & 15;
    const int bh = blockIdx.x >> 4, chunk = blockIdx.x & 15;

    bf16x8 pb[2][4];
    load_pfrags(Pm, wv, quad, l16, pb);

    // --- stage kv^T (bf16 transposed) + ksum, once per block ---
    const float* kvg = kv + (size_t)bh * MM * DD;
#pragma unroll
    for (int it = 0; it < 16; ++it) {
        int i = t + it * 256;          // float4 index over [256][16]
        int m = i >> 4, d4 = i & 15;
        float4 f = *(const float4*)(kvg + m * DD + d4 * 4);
        kvT[(d4 * 4 + 0) * 264 + m] = f2bf(f.x);
        kvT[(d4 * 4 + 1) * 264 + m] = f2bf(f.y);
        kvT[(d4 * 4 + 2) * 264 + m] = f2bf(f.z);
        kvT[(d4 * 4 + 3) * 264 + m] = f2bf(f.w);
    }
    ks_lds[t] = ksum[bh * MM + t];
    __syncthreads();
    float ksv[4];
#pragma unroll
    for (int mt = 0; mt < 4; ++mt) ksv[mt] = ks_lds[wv * 64 + mt * 16 + l16];

    const size_t base = ((size_t)bh * LL + (size_t)chunk * 512) * DD;
    const float* qb = qin + base;
    float* ob = out + base;
    const int sl = t >> 4, sd4 = t & 15;

    for (int tile = 0; tile < 16; ++tile) {
        __syncthreads();
        if (t < 32) z_lds[t] = 0.f;
#pragma unroll
        for (int half = 0; half < 2; ++half) {
            const int l = sl + half * 16;
            const int gi = (tile * 32 + l) * DD + sd4 * 4;
            float4 qf = *(const float4*)(qb + gi);
            float sq = qf.x * qf.x + qf.y * qf.y + qf.z * qf.z + qf.w * qf.w;
            sq += __shfl_xor(sq, 1); sq += __shfl_xor(sq, 2);
            sq += __shfl_xor(sq, 4); sq += __shfl_xor(sq, 8);
            if (sd4 == 0) cl_lds[l] = EPSK - SQS * sq;
            union { short s[4]; unsigned long long u; } uq;
            uq.s[0] = f2bf(qf.x); uq.s[1] = f2bf(qf.y);
            uq.s[2] = f2bf(qf.z); uq.s[3] = f2bf(qf.w);
            *(unsigned long long*)&Qb[l * 72 + sd4 * 4] = uq.u;
        }
        __syncthreads();
        // --- proj MFMA ---
        f32x4 pt[2][4];
#pragma unroll
        for (int lt = 0; lt < 2; ++lt)
#pragma unroll
            for (int mt = 0; mt < 4; ++mt) pt[lt][mt] = (f32x4)0.f;
#pragma unroll
        for (int ks = 0; ks < 2; ++ks)
#pragma unroll
            for (int lt = 0; lt < 2; ++lt) {
                bf16x8 af = *(bf16x8*)&Qb[(lt * 16 + l16) * 72 + ks * 32 + quad * 8];
#pragma unroll
                for (int mt = 0; mt < 4; ++mt)
                    pt[lt][mt] = MFMA(af, pb[ks][mt], pt[lt][mt]);
            }
        // --- exp -> Q' [l][m] in LDS, z partials in regs ---
        float cl[2][4];
#pragma unroll
        for (int lt = 0; lt < 2; ++lt)
#pragma unroll
            for (int r = 0; r < 4; ++r) cl[lt][r] = cl_lds[lt * 16 + quad * 4 + r];
        float zp[2][4] = {{0.f,0.f,0.f,0.f},{0.f,0.f,0.f,0.f}};
#pragma unroll
        for (int lt = 0; lt < 2; ++lt)
#pragma unroll
            for (int mt = 0; mt < 4; ++mt)
#pragma unroll
                for (int r = 0; r < 4; ++r) {
                    float w = __expf(pt[lt][mt][r] + cl[lt][r]);
                    zp[lt][r] += w * ksv[mt];
                    Qp[(lt * 16 + quad * 4 + r) * 264 + wv * 64 + mt * 16 + l16] = f2bf(w);
                }
        // z: reduce over the 16 m-lanes, then cross-wave via LDS atomic
#pragma unroll
        for (int lt = 0; lt < 2; ++lt)
#pragma unroll
            for (int r = 0; r < 4; ++r) {
                float vz = zp[lt][r];
                vz += __shfl_xor(vz, 1); vz += __shfl_xor(vz, 2);
                vz += __shfl_xor(vz, 4); vz += __shfl_xor(vz, 8);
                if (l16 == 0) atomicAdd(&z_lds[lt * 16 + quad * 4 + r], vz);
            }
        __syncthreads();
        // --- out MFMA: wave wv owns d-tile wv; K = m = 256 -> 8 steps ---
        f32x4 oc[2];
        oc[0] = (f32x4)0.f; oc[1] = (f32x4)0.f;
#pragma unroll
        for (int ks = 0; ks < 8; ++ks) {
            bf16x8 bk = *(bf16x8*)&kvT[(wv * 16 + l16) * 264 + ks * 32 + quad * 8];
#pragma unroll
            for (int lt = 0; lt < 2; ++lt) {
                bf16x8 aq = *(bf16x8*)&Qp[(lt * 16 + l16) * 264 + ks * 32 + quad * 8];
                oc[lt] = MFMA(aq, bk, oc[lt]);
            }
        }
#pragma unroll
        for (int lt = 0; lt < 2; ++lt)
#pragma unroll
            for (int r = 0; r < 4; ++r) {
                const int row = lt * 16 + quad * 4 + r;
                const float z = 1.f / (z_lds[row] + EPSZ);
                ob[(size_t)(tile * 32 + row) * DD + wv * 16 + l16] = oc[lt][r] * z;
            }
    }
}

extern "C" void kernel_launch(void* const* d_in, const int* in_sizes, int n_in,
                              void* d_out, int out_size, void* d_ws, size_t ws_size,
                              hipStream_t stream) {
    const float* q  = (const float*)d_in[0];
    const float* k  = (const float*)d_in[1];
    const float* v  = (const float*)d_in[2];
    const float* Pm = (const float*)d_in[3];

    float* kvw = (float*)d_ws;                       // [BH, M, D]
    float* ksw = kvw + (size_t)BH * MM * DD;         // [BH, M]

    hipMemsetAsync(d_ws, 0, ((size_t)BH * MM * DD + (size_t)BH * MM) * sizeof(float), stream);
    hipLaunchKernelGGL(kv_kernel, dim3(512), dim3(256), 0, stream, k, v, Pm, kvw, ksw);
    hipLaunchKernelGGL(out_kernel, dim3(512), dim3(256), 0, stream, q, Pm, kvw, ksw, (float*)d_out);
}